// Round 10
// baseline (439.716 us; speedup 1.0000x reference)
//
#include <hip/hip_runtime.h>
#include <hip/hip_cooperative_groups.h>
#include <math.h>

namespace cg = cooperative_groups;

#define N_NODES 100000
#define N_EDGES 1600000
#define D_FEAT 32
#define D_HID 64
#define D_OUT 64
#define CAP 48            // per-node slot capacity; deg ~ Poisson(16), safe
#define NPB 66            // nodes per bucket
#define NBKT 1536         // 1536 * 66 = 101376 >= 100000; 256 blocks * 6 each
#define ECAP 1280         // per-bucket edge capacity (mean 1042, +7 sigma)
#define NBLK 256          // grid: 1 block/CU guaranteed co-resident
#define THREADS 1024      // 16 waves
#define BPB 6             // buckets per block in phase 2 (256*6 = 1536)
#define BIN_BLOCKS 100    // phase-1 split: blocks [0,100) bin, [100,256) node
#define E_PER_BIN 16000   // 100 * 16000 = 1.6M edges

typedef short bf16x8 __attribute__((ext_vector_type(8)));
typedef float f32x4  __attribute__((ext_vector_type(4)));

__device__ inline unsigned short f2bf(float f) {   // RNE f32 -> bf16
    unsigned u = __float_as_uint(f);
    u += 0x7fff + ((u >> 16) & 1);
    return (unsigned short)(u >> 16);
}
__device__ inline float bf2f(unsigned short h) {
    return __uint_as_float(((unsigned)h) << 16);
}
__device__ inline unsigned pack2bf(float lo, float hi) {   // -> [hi|lo] u32
    return ((unsigned)f2bf(hi) << 16) | (unsigned)f2bf(lo);
}
// exact floor(d/66) for 0 <= d < ~4e8 (Granlund-Montgomery magic)
__device__ inline int bdiv66(int d) {
    return (int)((((unsigned long long)(unsigned)d) * 65075263ULL) >> 32);
}

union afu { uint4 u; bf16x8 v; };

// One A-fragment (8 bf16) from a packed vb row chunk and f32 q chunk:
// af[2m] = relu(lo16(w_m)-qk[2m]); af[2m+1] = relu(hi16(w_m)-qk[2m+1])
__device__ inline afu abuild(uint4 vv, const float* qk) {
    afu af;
#pragma unroll
    for (int m = 0; m < 4; ++m) {
        unsigned w = (&vv.x)[m];
        float flo = __uint_as_float(w << 16);
        float fhi = __uint_as_float(w & 0xFFFF0000u);
        float hlo = fmaxf(flo - qk[2 * m],     0.0f);
        float hhi = fmaxf(fhi - qk[2 * m + 1], 0.0f);
        (&af.u.x)[m] = pack2bf(hlo, hhi);
    }
    return af;
}

// ---------------------------------------------------------------------------
// Single cooperative kernel, 256 blocks x 1024 thr (1 block/CU: launch can
// never exceed cooperative capacity — round 9's 768x512 ask was rejected).
// Phase 1 (parallel block split):
//   blocks [0,100):   two-phase binning of 1.6M edges into 1536 buckets of
//                     66 dst-nodes (LDS histogram -> one global atomicAdd
//                     per bucket reserving a contiguous range -> placement
//                     via LDS cursors; entry = (src<<7)|(dst-bkt*66))
//   blocks [100,256): node precompute: q = pos@W1[32:35],
//                     v = b1 + x@W1[:32] + q (bf16 store); per-edge layer-1
//                     output is relu(v[src]-q[dst])
// threadfence + grid.sync()
// Phase 2 (all 256 blocks, 6 contiguous buckets each):
//   fine-bucket the bucket's dense edge list into per-node LDS slot lists,
//   then 16 waves aggregate ~4 nodes each: A[m][k]=relu(v[s_m][k]-q[i][k]),
//   layer-2 via 4x2 mfma_f32_16x16x32_bf16 per 16-row batch (slot index
//   prefetched one batch ahead), register max, bias, one coalesced store.
//   Padding rows use src=node (self-loop, idempotent under max).
// ---------------------------------------------------------------------------
__global__ __launch_bounds__(THREADS)
void mega_kernel(const float* __restrict__ x,
                 const float* __restrict__ pos,
                 const float* __restrict__ W1,
                 const float* __restrict__ b1,
                 const float* __restrict__ W2,
                 const float* __restrict__ b2,
                 const int* __restrict__ src,
                 const int* __restrict__ dst,
                 unsigned short* __restrict__ vb,
                 unsigned short* __restrict__ qb,
                 int* __restrict__ gcnt,
                 unsigned int* __restrict__ coarse,
                 float* __restrict__ out) {
    __shared__ int hist[NBKT];
    __shared__ int lcnt[NPB];
    __shared__ int lslots[NPB][CAP];

    cg::grid_group grid = cg::this_grid();

    const int tid  = threadIdx.x;
    const int lane = tid & 63;
    const int wave = tid >> 6;             // 0..15
    const int quad = lane >> 4;
    const int mrow = lane & 15;

    // ---------------- Phase 1 ----------------
    if (blockIdx.x < BIN_BLOCKS) {
        const int e0 = blockIdx.x * E_PER_BIN;
        const int4* d4p = (const int4*)(dst + e0);
        const int4* s4p = (const int4*)(src + e0);
        const int nq = E_PER_BIN / 4;      // 4000

        for (int b = tid; b < NBKT; b += THREADS) hist[b] = 0;
        __syncthreads();

        for (int i = tid; i < nq; i += THREADS) {
            int4 d4 = d4p[i];
            atomicAdd(&hist[bdiv66(d4.x)], 1);
            atomicAdd(&hist[bdiv66(d4.y)], 1);
            atomicAdd(&hist[bdiv66(d4.z)], 1);
            atomicAdd(&hist[bdiv66(d4.w)], 1);
        }
        __syncthreads();

        for (int b = tid; b < NBKT; b += THREADS) {
            int c = hist[b];
            hist[b] = (c > 0) ? atomicAdd(&gcnt[b], c) : 0;
        }
        __syncthreads();

        for (int i = tid; i < nq; i += THREADS) {
            int4 d4 = d4p[i];
            int4 s4 = s4p[i];
            int b0 = bdiv66(d4.x), b1i = bdiv66(d4.y);
            int b2i = bdiv66(d4.z), b3 = bdiv66(d4.w);
            int p0 = atomicAdd(&hist[b0], 1);
            int p1 = atomicAdd(&hist[b1i], 1);
            int p2 = atomicAdd(&hist[b2i], 1);
            int p3 = atomicAdd(&hist[b3], 1);
            if (p0 < ECAP) coarse[(size_t)b0 * ECAP + p0] = ((unsigned)s4.x << 7) | (unsigned)(d4.x - b0 * NPB);
            if (p1 < ECAP) coarse[(size_t)b1i * ECAP + p1] = ((unsigned)s4.y << 7) | (unsigned)(d4.y - b1i * NPB);
            if (p2 < ECAP) coarse[(size_t)b2i * ECAP + p2] = ((unsigned)s4.z << 7) | (unsigned)(d4.z - b2i * NPB);
            if (p3 < ECAP) coarse[(size_t)b3 * ECAP + p3] = ((unsigned)s4.w << 7) | (unsigned)(d4.w - b3 * NPB);
        }
    } else {
        // node precompute
        const int nb  = blockIdx.x - BIN_BLOCKS;
        const int wid = nb * 16 + wave;
        const int nw  = (NBLK - BIN_BLOCKS) * 16;   // 2496 waves

        float w[D_FEAT + 3];
#pragma unroll
        for (int f = 0; f < D_FEAT + 3; ++f)
            w[f] = W1[f * D_HID + lane];
        const float bb = b1[lane];

        for (int node = wid; node < N_NODES; node += nw) {
            const float* xr = x + (size_t)node * D_FEAT;
            float acc = bb;
#pragma unroll
            for (int f = 0; f < D_FEAT; ++f)
                acc = fmaf(xr[f], w[f], acc);

            const float* pr = pos + (size_t)node * 3;
            float qa = 0.0f;
#pragma unroll
            for (int p = 0; p < 3; ++p)
                qa = fmaf(pr[p], w[D_FEAT + p], qa);

            vb[(size_t)node * D_HID + lane] = f2bf(acc + qa);
            qb[(size_t)node * D_HID + lane] = f2bf(qa);
        }
    }

    __threadfence();
    grid.sync();

    // ---------------- Phase 2: aggregation ----------------
    // B fragments: bfrag[t][kh][j] = W2[kh*32 + quad*8 + j][t*16 + mrow]
    bf16x8 bfrag[4][2];
#pragma unroll
    for (int t = 0; t < 4; ++t)
#pragma unroll
        for (int kh = 0; kh < 2; ++kh) {
            bf16x8 f;
#pragma unroll
            for (int j = 0; j < 8; ++j)
                f[j] = (short)f2bf(W2[(kh * 32 + quad * 8 + j) * D_OUT + t * 16 + mrow]);
            bfrag[t][kh] = f;
        }
    float bias[4];
#pragma unroll
    for (int t = 0; t < 4; ++t) bias[t] = b2[t * 16 + mrow];

    const uint4* vbq = (const uint4*)vb;   // row = 8 uint4

    const int bkt0 = blockIdx.x * BPB;
    for (int bkt = bkt0; bkt < bkt0 + BPB; ++bkt) {
        __syncthreads();                   // protect LDS reuse across buckets
        for (int i = tid; i < NPB; i += THREADS) lcnt[i] = 0;
        __syncthreads();

        int E_b = gcnt[bkt];
        if (E_b > ECAP) E_b = ECAP;
        const unsigned int* crow = coarse + (size_t)bkt * ECAP;
        for (int i = tid; i < E_b; i += THREADS) {
            unsigned enc = crow[i];
            int ln = (int)(enc & 127u);
            int p = atomicAdd(&lcnt[ln], 1);
            if (p < CAP) lslots[ln][p] = (int)(enc >> 7);
        }
        __syncthreads();

        const int nbase = bkt * NPB;
        for (int ln = wave; ln < NPB; ln += 16) {
            const int node = nbase + ln;
            if (node >= N_NODES) break;

            float qf[2][8];
#pragma unroll
            for (int kh = 0; kh < 2; ++kh) {
                bf16x8 qv = *(const bf16x8*)(qb + (size_t)node * D_HID + kh * 32 + quad * 8);
#pragma unroll
                for (int j = 0; j < 8; ++j) qf[kh][j] = bf2f((unsigned short)qv[j]);
            }

            int deg = lcnt[ln];
            if (deg > CAP) deg = CAP;
            const int rows = deg + 1;          // + self-loop
            const int nbat = (rows + 15) >> 4;
            const int* lsl = lslots[ln];

            float rmax[4][4];
#pragma unroll
            for (int t = 0; t < 4; ++t)
#pragma unroll
                for (int r = 0; r < 4; ++r) rmax[t][r] = -INFINITY;

            int s_cur = (mrow < deg) ? lsl[mrow] : node;
            for (int b = 0; b < nbat; ++b) {
                int idx = (b + 1) * 16 + mrow;
                int s_nxt = (idx < deg) ? lsl[idx] : node;   // prefetch

                const uint4* pa = vbq + (size_t)s_cur * 8 + quad;
                uint4 v0 = pa[0], v1 = pa[4];  // kh=0 / kh=1 chunks

                afu a0 = abuild(v0, qf[0]);
                afu a1 = abuild(v1, qf[1]);

#pragma unroll
                for (int t = 0; t < 4; ++t) {
                    f32x4 acc = (f32x4){0.f, 0.f, 0.f, 0.f};
                    acc = __builtin_amdgcn_mfma_f32_16x16x32_bf16(a0.v, bfrag[t][0], acc, 0, 0, 0);
                    acc = __builtin_amdgcn_mfma_f32_16x16x32_bf16(a1.v, bfrag[t][1], acc, 0, 0, 0);
#pragma unroll
                    for (int r = 0; r < 4; ++r)
                        rmax[t][r] = fmaxf(rmax[t][r], acc[r]);
                }
                s_cur = s_nxt;
            }

            float fin[4];
#pragma unroll
            for (int t = 0; t < 4; ++t) {
                float m = fmaxf(fmaxf(rmax[t][0], rmax[t][1]), fmaxf(rmax[t][2], rmax[t][3]));
                m = fmaxf(m, __shfl_xor(m, 16, 64));
                m = fmaxf(m, __shfl_xor(m, 32, 64));
                fin[t] = m + bias[t];
            }
            float r = (quad == 0) ? fin[0] : (quad == 1) ? fin[1] : (quad == 2) ? fin[2] : fin[3];
            out[(size_t)node * D_OUT + lane] = r;
        }
    }
}

// ---------------------------------------------------------------------------
extern "C" void kernel_launch(void* const* d_in, const int* in_sizes, int n_in,
                              void* d_out, int out_size, void* d_ws, size_t ws_size,
                              hipStream_t stream) {
    const float* x   = (const float*)d_in[0];
    const float* pos = (const float*)d_in[1];
    const int*   ei  = (const int*)d_in[2];   // [2][N_EDGES]: row0=src, row1=dst
    const float* W1  = (const float*)d_in[3];
    const float* b1  = (const float*)d_in[4];
    const float* W2  = (const float*)d_in[5];
    const float* b2  = (const float*)d_in[6];
    float* out = (float*)d_out;

    char* ws = (char*)d_ws;
    unsigned short* vb   = (unsigned short*)ws;                     // 12.8 MB
    unsigned short* qb   = (unsigned short*)(ws + 12800000);        // 12.8 MB
    int*            gcnt = (int*)(ws + 25600000);                   // 6.1 KB
    unsigned int* coarse = (unsigned int*)(ws + 25610240);          // 7.9 MB

    const int* src = ei;
    const int* dst = ei + N_EDGES;

    (void)hipMemsetAsync(gcnt, 0, NBKT * sizeof(int), stream);

    void* args[] = {(void*)&x, (void*)&pos, (void*)&W1, (void*)&b1,
                    (void*)&W2, (void*)&b2, (void*)&src, (void*)&dst,
                    (void*)&vb, (void*)&qb, (void*)&gcnt, (void*)&coarse,
                    (void*)&out};
    (void)hipLaunchCooperativeKernel((void*)mega_kernel, dim3(NBLK), dim3(THREADS),
                                     args, 0, stream);
}